// Round 7
// baseline (148.343 us; speedup 1.0000x reference)
//
#include <hip/hip_runtime.h>
#include <hip/hip_bf16.h>
#include <math.h>

#define BS   128
#define NT   25
#define CREC 107
#define CLOC 25
#define QN   1024      // H*W = 32*32 queries = columns of the transposed cost
#define INFD 1e18

// focal-loss matcher cost. Fast transcendentals: the matcher only needs the
// optimal assignment, robust to ~1e-7 cost perturbation (absmax 0.0 across
// many verified rounds).
__device__ __forceinline__ float focal_cost_f(float x) {
    float p   = 1.0f / (1.0f + __expf(-x));
    float neg = 0.75f * p * p * (-__logf(1.0f - p + 1e-8f));
    float pos = 0.25f * (1.0f - p) * (1.0f - p) * (-__logf(p + 1e-8f));
    return pos - neg;
}

// One block per cost row (b,r): computes the row's costs, STORES them to
// global (L3-hot for search), and reduces min + first-index argmin exactly.
// 3200 blocks => full memory-latency hiding.
__global__ __launch_bounds__(256)
void rowmin_kernel(const float* __restrict__ rec, const float* __restrict__ loc,
                   const int* __restrict__ targets, float* __restrict__ cost_g,
                   float* __restrict__ rowmin_g, int* __restrict__ rowarg_g) {
    const int pid   = blockIdx.x;          // b*NT + r
    const int b     = pid / NT, r = pid % NT;
    const int tid   = threadIdx.x;
    const int qbase = tid << 2;
    const int tc    = targets[pid];

    float4 r4 = *(const float4*)(rec + ((size_t)b * CREC + tc) * QN + qbase);
    float4 l4 = *(const float4*)(loc + ((size_t)b * CLOC + r)  * QN + qbase);
    float4 c;
    c.x = 2.0f * focal_cost_f(r4.x) + focal_cost_f(l4.x);
    c.y = 2.0f * focal_cost_f(r4.y) + focal_cost_f(l4.y);
    c.z = 2.0f * focal_cost_f(r4.z) + focal_cost_f(l4.z);
    c.w = 2.0f * focal_cost_f(r4.w) + focal_cost_f(l4.w);
    *(float4*)(cost_g + ((size_t)pid << 10) + qbase) = c;

    float bv = c.x; int bq = qbase;
    if (c.y < bv) { bv = c.y; bq = qbase + 1; }     // strict < => first index
    if (c.z < bv) { bv = c.z; bq = qbase + 2; }
    if (c.w < bv) { bv = c.w; bq = qbase + 3; }
    #pragma unroll
    for (int off = 32; off; off >>= 1) {
        float ov = __shfl_xor(bv, off);
        int   oq = __shfl_xor(bq, off);
        if (ov < bv || (ov == bv && oq < bq)) { bv = ov; bq = oq; }
    }
    __shared__ float bmv[4];
    __shared__ int   bmq[4];
    if ((tid & 63) == 0) { bmv[tid >> 6] = bv; bmq[tid >> 6] = bq; }
    __syncthreads();
    if (tid == 0) {
        float fv = bmv[0]; int fq = bmq[0];
        #pragma unroll
        for (int w = 1; w < 4; ++w) {
            float ov = bmv[w]; int oq = bmq[w];
            if (ov < fv || (ov == fv && oq < fq)) { fv = ov; fq = oq; }
        }
        rowmin_g[pid] = fv; rowarg_g[pid] = fq;
    }
}

// ONE WAVE (64 threads) per batch: greedy tight assignment from row minima,
// then JV shortest-augmenting-path for argmin-collided rows. Thread t owns
// columns c == t (mod 64), 16 slots each. When any search is needed (~94%
// of batches), the batch's whole 25x1024 cost slab (100 KB) is prefetched
// into dynamic LDS once (~1 us, coalesced float4); every JV iteration's row
// read becomes 16 conflict-free ds_read_b32 (~150 cy) instead of 16 global
// loads (~500-800 cy). In the barrier-free 1-wave structure this is the
// largest remaining segment of the serial chain.
// Same algorithm semantics as the verified R0/R5 kernels: strict-< relax,
// snap/dsum dual bookkeeping, f32-monotone-screened exact-f64 wave argmin,
// f64 duals on the same f32 cost values = exact numpy float64 JV => the
// unique optimal assignment = scipy's answer.
__global__ __launch_bounds__(64)
void search_kernel(const float* __restrict__ cost_g,
                   const float* __restrict__ rowmin_g, const int* __restrict__ rowarg_g,
                   int* __restrict__ pairq_g) {
    const int b    = blockIdx.x;
    const int lane = threadIdx.x;        // 0..63

    extern __shared__ float cost_s[];    // f32[NT*QN] = 100 KB dynamic
    __shared__ int    way_s[QN + 1];
    __shared__ int    p_s[QN + 1];
    __shared__ double u_s[NT + 1];
    __shared__ float  rowmin_s[NT];
    __shared__ int    rowarg_s[NT];
    __shared__ int    unassigned_s[NT];
    __shared__ int    nun_s;

    for (int j = lane; j <= QN; j += 64) p_s[j] = 0;
    if (lane < NT) {
        rowmin_s[lane] = rowmin_g[b * NT + lane];
        rowarg_s[lane] = rowarg_g[b * NT + lane];
    }
    __syncthreads();

    // greedy tight assignment (serial, trivial)
    if (lane == 0) {
        int nun = 0;
        for (int r = 0; r < NT; ++r) {
            u_s[r + 1] = (double)rowmin_s[r];
            int j = rowarg_s[r] + 1;
            if (p_s[j] == 0) p_s[j] = r + 1;
            else             unassigned_s[nun++] = r + 1;
        }
        nun_s = nun;
    }
    __syncthreads();
    const int nun = nun_s;

    if (nun > 0) {
        // prefetch the whole 25x1024 cost slab into LDS (coalesced float4;
        // wave-uniform branch, 1-wave block => __syncthreads is ~free)
        const float4* src = (const float4*)(cost_g + ((size_t)b * NT << 10));
        float4*       dst = (float4*)cost_s;
        #pragma unroll 4
        for (int idx = lane; idx < NT * 256; idx += 64) dst[idx] = src[idx];
        __syncthreads();

        double v[16];
        #pragma unroll
        for (int m = 0; m < 16; ++m) v[m] = 0.0;

        for (int s = 0; s < nun; ++s) {
            const int i = unassigned_s[s];
            double minv[16], snap[16];
            #pragma unroll
            for (int m = 0; m < 16; ++m) { minv[m] = INFD; snap[m] = 0.0; }
            double dsum = 0.0;
            unsigned usedmask = 0;
            int j0 = 0;

            for (;;) {
                int i0;
                if (j0 == 0) {
                    i0 = i;
                } else {
                    int q0 = j0 - 1;
                    if ((q0 & 63) == lane) {         // owner lane of column q0
                        int mm = q0 >> 6;
                        usedmask |= 1u << mm;
                        #pragma unroll                // static indices only
                        for (int m = 0; m < 16; ++m)
                            if (m == mm) { minv[m] = INFD; snap[m] = dsum; }
                    }
                    i0 = p_s[j0];                    // p stable within a search
                }
                const double ui0 = u_s[i0];          // pre-search value (read-only in-loop)
                const float* rowp = cost_s + ((i0 - 1) << 10);
                float cf[16];
                #pragma unroll                        // conflict-free: lanes hit consecutive dwords
                for (int m = 0; m < 16; ++m) cf[m] = rowp[(m << 6) + lane];

                // relax own free columns; lane-local lexicographic argmin
                // (ascending m == ascending j within a lane)
                double bestv = INFD; int bestj = QN + 2;
                #pragma unroll
                for (int m = 0; m < 16; ++m) {
                    if (!(usedmask & (1u << m))) {
                        const int j = (m << 6) + lane + 1;
                        double cur = (double)cf[m] - ui0 - v[m];
                        if (cur < minv[m]) { minv[m] = cur; way_s[j] = j0; }
                        double mv = minv[m];
                        if (mv < bestv || (mv == bestv && j < bestj)) { bestv = mv; bestj = j; }
                    }
                }

                // f32-screened wave argmin over ALL 64 lanes: monotone screen,
                // exact f64 resolve; every lane ends with the global (wv, wj).
                float own32 = (float)bestv;
                float w32 = own32;
                #pragma unroll
                for (int off = 32; off; off >>= 1) w32 = fminf(w32, __shfl_xor(w32, off));
                unsigned long long cand = __ballot(own32 == w32);
                double wv = INFD; int wj = QN + 2;
                while (cand) {                       // ~1 iteration typical, wave-uniform
                    int l = __ffsll(cand) - 1; cand &= cand - 1;
                    double vv = __shfl(bestv, l);
                    int    jj = __shfl(bestj, l);
                    if (vv < wv || (vv == wv && jj < wj)) { wv = vv; wj = jj; }
                }
                const double delta = wv; const int j1 = wj;
                dsum += delta;

                #pragma unroll
                for (int m = 0; m < 16; ++m) {
                    if (usedmask & (1u << m)) v[m]    -= delta;
                    else                      minv[m] -= delta;
                }
                j0 = j1;
                if (p_s[j0] == 0) break;
            }

            // end-of-search u updates: distinct used columns => distinct
            // assigned rows => distinct LDS addresses, no race
            if (lane == 0) u_s[i] += dsum;
            unsigned mm = usedmask;
            while (mm) {
                int m = __ffs(mm) - 1; mm &= mm - 1;
                u_s[p_s[(m << 6) + lane + 1]] += dsum - snap[m];
            }
            __syncthreads();   // way_s/u_s visible to lane 0 (1-wave: cheap)
            // augment along the alternating path (short, sequential)
            if (lane == 0) {
                int jj = j0;
                while (jj != 0) {
                    int jn = way_s[jj];
                    p_s[jj] = (jn == 0) ? i : p_s[jn];
                    jj = jn;
                }
            }
            __syncthreads();   // p_s visible to all lanes for next search
        }
    }

    // emit matched pairs: column j assigned to target row p_s[j]-1
    for (int j = lane + 1; j <= QN; j += 64)
        if (p_s[j] > 0) pairq_g[b * NT + (p_s[j] - 1)] = j - 1;
}

// One wave per matched pair: CE over 107 (rec) and 25 (loc) classes at the
// matched query column. 3200 blocks => full latency hiding for the gathers.
// NO fences/atomics here — R3 showed per-block __threadfence() costs ~130 us
// (3200 device-scope flushes on non-coherent XCD L2s). The cross-kernel
// handoff to finalize_kernel does the cache maintenance ONCE at the boundary.
__global__ __launch_bounds__(64)
void loss_kernel(const float* __restrict__ rec, const float* __restrict__ loc,
                 const int* __restrict__ targets, const int* __restrict__ pairq_g,
                 float* __restrict__ partial) {
    const int pid  = blockIdx.x;          // b*NT + t
    const int b    = pid / NT, t = pid % NT;
    const int lane = threadIdx.x;
    const int q    = pairq_g[pid];

    // rec CE over 107 classes at query q
    const float* rb = rec + (size_t)b * CREC * QN + q;
    float x0 = (lane < CREC)      ? rb[(size_t)lane * QN]        : -1e30f;
    float x1 = (lane + 64 < CREC) ? rb[(size_t)(lane + 64) * QN] : -1e30f;
    float mx = fmaxf(x0, x1);
    #pragma unroll
    for (int off = 32; off; off >>= 1) mx = fmaxf(mx, __shfl_xor(mx, off));
    float e = 0.0f;
    if (lane < CREC)      e += expf(x0 - mx);
    if (lane + 64 < CREC) e += expf(x1 - mx);
    #pragma unroll
    for (int off = 32; off; off >>= 1) e += __shfl_xor(e, off);
    float lse = mx + logf(e);

    // loc CE over 25 classes at query q, label = t
    const float* lb = loc + (size_t)b * CLOC * QN + q;
    float y = (lane < CLOC) ? lb[(size_t)lane * QN] : -1e30f;
    float my = y;
    #pragma unroll
    for (int off = 32; off; off >>= 1) my = fmaxf(my, __shfl_xor(my, off));
    float ey = (lane < CLOC) ? expf(y - my) : 0.0f;
    #pragma unroll
    for (int off = 32; off; off >>= 1) ey += __shfl_xor(ey, off);
    float lsey = my + logf(ey);

    if (lane == 0) {
        int lab = targets[pid];
        partial[pid]           = lse  - rb[(size_t)lab * QN];
        partial[BS * NT + pid] = lsey - lb[(size_t)t * QN];
    }
}

__global__ __launch_bounds__(256)
void finalize_kernel(const float* __restrict__ partial, float* __restrict__ out) {
    const int tid = threadIdx.x;
    float s0 = 0.0f, s1 = 0.0f;
    for (int i = tid; i < BS * NT; i += 256) {
        s0 += partial[i];
        s1 += partial[BS * NT + i];
    }
    __shared__ float a0[4], a1[4];
    #pragma unroll
    for (int off = 32; off; off >>= 1) { s0 += __shfl_xor(s0, off); s1 += __shfl_xor(s1, off); }
    if ((tid & 63) == 0) { a0[tid >> 6] = s0; a1[tid >> 6] = s1; }
    __syncthreads();
    if (tid == 0) {
        out[0] = (a0[0] + a0[1] + a0[2] + a0[3]) * (1.0f / (BS * NT));
        out[1] = (a1[0] + a1[1] + a1[2] + a1[3]) * (1.0f / (BS * NT));
    }
}

extern "C" void kernel_launch(void* const* d_in, const int* in_sizes, int n_in,
                              void* d_out, int out_size, void* d_ws, size_t ws_size,
                              hipStream_t stream) {
    (void)in_sizes; (void)n_in; (void)out_size; (void)ws_size;
    const float* rec     = (const float*)d_in[0];
    const float* loc     = (const float*)d_in[1];
    const int*   targets = (const int*)d_in[2];
    float* out = (float*)d_out;

    // ws layout: cost f32[BS*NT*QN]=13.1MB | rowmin f32[3200] | rowarg i32[3200]
    //            | pairq i32[3200] | partial f32[6400]
    float* cost_g   = (float*)d_ws;
    float* rowmin_g = cost_g + (size_t)BS * NT * QN;
    int*   rowarg_g = (int*)(rowmin_g + BS * NT);
    int*   pairq_g  = rowarg_g + BS * NT;
    float* partial  = (float*)(pairq_g + BS * NT);

    // >64KB dynamic LDS opt-in for search (host-side attribute; not a
    // stream op — safe under graph capture).
    static bool attr_set = false;
    if (!attr_set) {
        (void)hipFuncSetAttribute((const void*)search_kernel,
                                  hipFuncAttributeMaxDynamicSharedMemorySize,
                                  (int)(NT * QN * sizeof(float)));
        attr_set = true;
    }

    hipLaunchKernelGGL(rowmin_kernel, dim3(BS * NT), dim3(256), 0, stream,
                       rec, loc, targets, cost_g, rowmin_g, rowarg_g);
    hipLaunchKernelGGL(search_kernel, dim3(BS), dim3(64),
                       NT * QN * sizeof(float), stream,
                       cost_g, rowmin_g, rowarg_g, pairq_g);
    hipLaunchKernelGGL(loss_kernel, dim3(BS * NT), dim3(64), 0, stream,
                       rec, loc, targets, pairq_g, partial);
    hipLaunchKernelGGL(finalize_kernel, dim3(1), dim3(256), 0, stream,
                       partial, out);
}

// Round 8
// 144.065 us; speedup vs baseline: 1.0297x; 1.0297x over previous
//
#include <hip/hip_runtime.h>
#include <hip/hip_bf16.h>
#include <math.h>

#define BS   128
#define NT   25
#define CREC 107
#define CLOC 25
#define QN   1024      // H*W = 32*32 queries = columns of the transposed cost
#define INFD 1e18

// focal-loss matcher cost. Fast transcendentals: the matcher only needs the
// optimal assignment, robust to ~1e-7 cost perturbation (absmax 0.0 across
// many verified rounds).
__device__ __forceinline__ float focal_cost_f(float x) {
    float p   = 1.0f / (1.0f + __expf(-x));
    float neg = 0.75f * p * p * (-__logf(1.0f - p + 1e-8f));
    float pos = 0.25f * (1.0f - p) * (1.0f - p) * (-__logf(p + 1e-8f));
    return pos - neg;
}

// One block per cost row (b,r): computes the row's costs, STORES them to
// global (L3-hot for search), and reduces min + first-index argmin exactly.
// 3200 blocks => full memory-latency hiding.
__global__ __launch_bounds__(256)
void rowmin_kernel(const float* __restrict__ rec, const float* __restrict__ loc,
                   const int* __restrict__ targets, float* __restrict__ cost_g,
                   float* __restrict__ rowmin_g, int* __restrict__ rowarg_g) {
    const int pid   = blockIdx.x;          // b*NT + r
    const int b     = pid / NT, r = pid % NT;
    const int tid   = threadIdx.x;
    const int qbase = tid << 2;
    const int tc    = targets[pid];

    float4 r4 = *(const float4*)(rec + ((size_t)b * CREC + tc) * QN + qbase);
    float4 l4 = *(const float4*)(loc + ((size_t)b * CLOC + r)  * QN + qbase);
    float4 c;
    c.x = 2.0f * focal_cost_f(r4.x) + focal_cost_f(l4.x);
    c.y = 2.0f * focal_cost_f(r4.y) + focal_cost_f(l4.y);
    c.z = 2.0f * focal_cost_f(r4.z) + focal_cost_f(l4.z);
    c.w = 2.0f * focal_cost_f(r4.w) + focal_cost_f(l4.w);
    *(float4*)(cost_g + ((size_t)pid << 10) + qbase) = c;

    float bv = c.x; int bq = qbase;
    if (c.y < bv) { bv = c.y; bq = qbase + 1; }     // strict < => first index
    if (c.z < bv) { bv = c.z; bq = qbase + 2; }
    if (c.w < bv) { bv = c.w; bq = qbase + 3; }
    #pragma unroll
    for (int off = 32; off; off >>= 1) {
        float ov = __shfl_xor(bv, off);
        int   oq = __shfl_xor(bq, off);
        if (ov < bv || (ov == bv && oq < bq)) { bv = ov; bq = oq; }
    }
    __shared__ float bmv[4];
    __shared__ int   bmq[4];
    if ((tid & 63) == 0) { bmv[tid >> 6] = bv; bmq[tid >> 6] = bq; }
    __syncthreads();
    if (tid == 0) {
        float fv = bmv[0]; int fq = bmq[0];
        #pragma unroll
        for (int w = 1; w < 4; ++w) {
            float ov = bmv[w]; int oq = bmq[w];
            if (ov < fv || (ov == fv && oq < fq)) { fv = ov; fq = oq; }
        }
        rowmin_g[pid] = fv; rowarg_g[pid] = fq;
    }
}

// ONE WAVE (64 threads) per batch: greedy tight assignment from row minima,
// then JV shortest-augmenting-path for argmin-collided rows. Thread t owns
// columns c == t (mod 64), 16 slots each. The batch's whole 25x1024 cost
// slab (100 KB) is prefetched into dynamic LDS with a DEEP-PIPELINED copy:
// 20 float4 loads issued back-to-back into registers (static indices) per
// chunk, ONE latency round-trip per chunk, 5 chunks => ~2 us wall (R7's
// unroll-4 version serialized ~100 round trips => ~28 us, eating the whole
// LDS win). Every JV iteration's row read is then 16 conflict-free
// ds_read_b32 (~150 cy) instead of 16 global loads (~700 cy) in a purely
// serial chain.
// Same algorithm semantics as the verified R0/R5/R7 kernels: strict-< relax,
// snap/dsum dual bookkeeping, f32-monotone-screened exact-f64 wave argmin,
// f64 duals on the same f32 cost values = exact numpy float64 JV => the
// unique optimal assignment = scipy's answer.
__global__ __launch_bounds__(64)
void search_kernel(const float* __restrict__ cost_g,
                   const float* __restrict__ rowmin_g, const int* __restrict__ rowarg_g,
                   int* __restrict__ pairq_g) {
    const int b    = blockIdx.x;
    const int lane = threadIdx.x;        // 0..63

    extern __shared__ float cost_s[];    // f32[NT*QN] = 100 KB dynamic
    __shared__ int    way_s[QN + 1];
    __shared__ int    p_s[QN + 1];
    __shared__ double u_s[NT + 1];
    __shared__ float  rowmin_s[NT];
    __shared__ int    rowarg_s[NT];
    __shared__ int    unassigned_s[NT];
    __shared__ int    nun_s;

    for (int j = lane; j <= QN; j += 64) p_s[j] = 0;
    if (lane < NT) {
        rowmin_s[lane] = rowmin_g[b * NT + lane];
        rowarg_s[lane] = rowarg_g[b * NT + lane];
    }
    __syncthreads();

    // greedy tight assignment (serial, trivial)
    if (lane == 0) {
        int nun = 0;
        for (int r = 0; r < NT; ++r) {
            u_s[r + 1] = (double)rowmin_s[r];
            int j = rowarg_s[r] + 1;
            if (p_s[j] == 0) p_s[j] = r + 1;
            else             unassigned_s[nun++] = r + 1;
        }
        nun_s = nun;
    }
    __syncthreads();
    const int nun = nun_s;

    if (nun > 0) {
        // deep-pipelined prefetch: 6400 float4 total / 64 lanes = 100 per
        // lane, in 5 chunks of 20 (20 loads in flight per chunk => one
        // round-trip each; all indices static => registers, no scratch)
        const float4* src = (const float4*)(cost_g + ((size_t)b * NT << 10));
        float4*       dst = (float4*)cost_s;
        #pragma unroll
        for (int ch = 0; ch < 5; ++ch) {
            float4 tmp[20];
            #pragma unroll
            for (int it = 0; it < 20; ++it)
                tmp[it] = src[(ch * 20 + it) * 64 + lane];
            #pragma unroll
            for (int it = 0; it < 20; ++it)
                dst[(ch * 20 + it) * 64 + lane] = tmp[it];
        }
        __syncthreads();

        double v[16];
        #pragma unroll
        for (int m = 0; m < 16; ++m) v[m] = 0.0;

        for (int s = 0; s < nun; ++s) {
            const int i = unassigned_s[s];
            double minv[16], snap[16];
            #pragma unroll
            for (int m = 0; m < 16; ++m) { minv[m] = INFD; snap[m] = 0.0; }
            double dsum = 0.0;
            unsigned usedmask = 0;
            int j0 = 0;

            for (;;) {
                int i0;
                if (j0 == 0) {
                    i0 = i;
                } else {
                    int q0 = j0 - 1;
                    if ((q0 & 63) == lane) {         // owner lane of column q0
                        int mm = q0 >> 6;
                        usedmask |= 1u << mm;
                        #pragma unroll                // static indices only
                        for (int m = 0; m < 16; ++m)
                            if (m == mm) { minv[m] = INFD; snap[m] = dsum; }
                    }
                    i0 = p_s[j0];                    // p stable within a search
                }
                const double ui0 = u_s[i0];          // pre-search value (read-only in-loop)
                const float* rowp = cost_s + ((i0 - 1) << 10);
                float cf[16];
                #pragma unroll                        // conflict-free: lanes hit consecutive dwords
                for (int m = 0; m < 16; ++m) cf[m] = rowp[(m << 6) + lane];

                // relax own free columns; lane-local lexicographic argmin
                // (ascending m == ascending j within a lane)
                double bestv = INFD; int bestj = QN + 2;
                #pragma unroll
                for (int m = 0; m < 16; ++m) {
                    if (!(usedmask & (1u << m))) {
                        const int j = (m << 6) + lane + 1;
                        double cur = (double)cf[m] - ui0 - v[m];
                        if (cur < minv[m]) { minv[m] = cur; way_s[j] = j0; }
                        double mv = minv[m];
                        if (mv < bestv || (mv == bestv && j < bestj)) { bestv = mv; bestj = j; }
                    }
                }

                // f32-screened wave argmin over ALL 64 lanes: monotone screen,
                // exact f64 resolve; every lane ends with the global (wv, wj).
                float own32 = (float)bestv;
                float w32 = own32;
                #pragma unroll
                for (int off = 32; off; off >>= 1) w32 = fminf(w32, __shfl_xor(w32, off));
                unsigned long long cand = __ballot(own32 == w32);
                double wv = INFD; int wj = QN + 2;
                while (cand) {                       // ~1 iteration typical, wave-uniform
                    int l = __ffsll(cand) - 1; cand &= cand - 1;
                    double vv = __shfl(bestv, l);
                    int    jj = __shfl(bestj, l);
                    if (vv < wv || (vv == wv && jj < wj)) { wv = vv; wj = jj; }
                }
                const double delta = wv; const int j1 = wj;
                dsum += delta;

                #pragma unroll
                for (int m = 0; m < 16; ++m) {
                    if (usedmask & (1u << m)) v[m]    -= delta;
                    else                      minv[m] -= delta;
                }
                j0 = j1;
                if (p_s[j0] == 0) break;
            }

            // end-of-search u updates: distinct used columns => distinct
            // assigned rows => distinct LDS addresses, no race
            if (lane == 0) u_s[i] += dsum;
            unsigned mm = usedmask;
            while (mm) {
                int m = __ffs(mm) - 1; mm &= mm - 1;
                u_s[p_s[(m << 6) + lane + 1]] += dsum - snap[m];
            }
            __syncthreads();   // way_s/u_s visible to lane 0 (1-wave: cheap)
            // augment along the alternating path (short, sequential)
            if (lane == 0) {
                int jj = j0;
                while (jj != 0) {
                    int jn = way_s[jj];
                    p_s[jj] = (jn == 0) ? i : p_s[jn];
                    jj = jn;
                }
            }
            __syncthreads();   // p_s visible to all lanes for next search
        }
    }

    // emit matched pairs: column j assigned to target row p_s[j]-1
    for (int j = lane + 1; j <= QN; j += 64)
        if (p_s[j] > 0) pairq_g[b * NT + (p_s[j] - 1)] = j - 1;
}

// One wave per matched pair: CE over 107 (rec) and 25 (loc) classes at the
// matched query column. 3200 blocks => full latency hiding for the gathers.
// NO fences/atomics here — R3 showed per-block __threadfence() costs ~130 us
// (3200 device-scope flushes on non-coherent XCD L2s). The cross-kernel
// handoff to finalize_kernel does the cache maintenance ONCE at the boundary.
__global__ __launch_bounds__(64)
void loss_kernel(const float* __restrict__ rec, const float* __restrict__ loc,
                 const int* __restrict__ targets, const int* __restrict__ pairq_g,
                 float* __restrict__ partial) {
    const int pid  = blockIdx.x;          // b*NT + t
    const int b    = pid / NT, t = pid % NT;
    const int lane = threadIdx.x;
    const int q    = pairq_g[pid];

    // rec CE over 107 classes at query q
    const float* rb = rec + (size_t)b * CREC * QN + q;
    float x0 = (lane < CREC)      ? rb[(size_t)lane * QN]        : -1e30f;
    float x1 = (lane + 64 < CREC) ? rb[(size_t)(lane + 64) * QN] : -1e30f;
    float mx = fmaxf(x0, x1);
    #pragma unroll
    for (int off = 32; off; off >>= 1) mx = fmaxf(mx, __shfl_xor(mx, off));
    float e = 0.0f;
    if (lane < CREC)      e += expf(x0 - mx);
    if (lane + 64 < CREC) e += expf(x1 - mx);
    #pragma unroll
    for (int off = 32; off; off >>= 1) e += __shfl_xor(e, off);
    float lse = mx + logf(e);

    // loc CE over 25 classes at query q, label = t
    const float* lb = loc + (size_t)b * CLOC * QN + q;
    float y = (lane < CLOC) ? lb[(size_t)lane * QN] : -1e30f;
    float my = y;
    #pragma unroll
    for (int off = 32; off; off >>= 1) my = fmaxf(my, __shfl_xor(my, off));
    float ey = (lane < CLOC) ? expf(y - my) : 0.0f;
    #pragma unroll
    for (int off = 32; off; off >>= 1) ey += __shfl_xor(ey, off);
    float lsey = my + logf(ey);

    if (lane == 0) {
        int lab = targets[pid];
        partial[pid]           = lse  - rb[(size_t)lab * QN];
        partial[BS * NT + pid] = lsey - lb[(size_t)t * QN];
    }
}

__global__ __launch_bounds__(256)
void finalize_kernel(const float* __restrict__ partial, float* __restrict__ out) {
    const int tid = threadIdx.x;
    float s0 = 0.0f, s1 = 0.0f;
    for (int i = tid; i < BS * NT; i += 256) {
        s0 += partial[i];
        s1 += partial[BS * NT + i];
    }
    __shared__ float a0[4], a1[4];
    #pragma unroll
    for (int off = 32; off; off >>= 1) { s0 += __shfl_xor(s0, off); s1 += __shfl_xor(s1, off); }
    if ((tid & 63) == 0) { a0[tid >> 6] = s0; a1[tid >> 6] = s1; }
    __syncthreads();
    if (tid == 0) {
        out[0] = (a0[0] + a0[1] + a0[2] + a0[3]) * (1.0f / (BS * NT));
        out[1] = (a1[0] + a1[1] + a1[2] + a1[3]) * (1.0f / (BS * NT));
    }
}

extern "C" void kernel_launch(void* const* d_in, const int* in_sizes, int n_in,
                              void* d_out, int out_size, void* d_ws, size_t ws_size,
                              hipStream_t stream) {
    (void)in_sizes; (void)n_in; (void)out_size; (void)ws_size;
    const float* rec     = (const float*)d_in[0];
    const float* loc     = (const float*)d_in[1];
    const int*   targets = (const int*)d_in[2];
    float* out = (float*)d_out;

    // ws layout: cost f32[BS*NT*QN]=13.1MB | rowmin f32[3200] | rowarg i32[3200]
    //            | pairq i32[3200] | partial f32[6400]
    float* cost_g   = (float*)d_ws;
    float* rowmin_g = cost_g + (size_t)BS * NT * QN;
    int*   rowarg_g = (int*)(rowmin_g + BS * NT);
    int*   pairq_g  = rowarg_g + BS * NT;
    float* partial  = (float*)(pairq_g + BS * NT);

    // >64KB dynamic LDS opt-in for search (host-side attribute; not a
    // stream op — safe under graph capture).
    static bool attr_set = false;
    if (!attr_set) {
        (void)hipFuncSetAttribute((const void*)search_kernel,
                                  hipFuncAttributeMaxDynamicSharedMemorySize,
                                  (int)(NT * QN * sizeof(float)));
        attr_set = true;
    }

    hipLaunchKernelGGL(rowmin_kernel, dim3(BS * NT), dim3(256), 0, stream,
                       rec, loc, targets, cost_g, rowmin_g, rowarg_g);
    hipLaunchKernelGGL(search_kernel, dim3(BS), dim3(64),
                       NT * QN * sizeof(float), stream,
                       cost_g, rowmin_g, rowarg_g, pairq_g);
    hipLaunchKernelGGL(loss_kernel, dim3(BS * NT), dim3(64), 0, stream,
                       rec, loc, targets, pairq_g, partial);
    hipLaunchKernelGGL(finalize_kernel, dim3(1), dim3(256), 0, stream,
                       partial, out);
}

// Round 9
// 142.769 us; speedup vs baseline: 1.0390x; 1.0091x over previous
//
#include <hip/hip_runtime.h>
#include <hip/hip_bf16.h>
#include <math.h>

#define BS   128
#define NT   25
#define CREC 107
#define CLOC 25
#define QN   1024      // H*W = 32*32 queries = columns of the transposed cost
#define INFD 1e18

// focal-loss matcher cost. Fast transcendentals: the matcher only needs the
// optimal assignment, robust to ~1e-7 cost perturbation (absmax 0.0 across
// many verified rounds).
__device__ __forceinline__ float focal_cost_f(float x) {
    float p   = 1.0f / (1.0f + __expf(-x));
    float neg = 0.75f * p * p * (-__logf(1.0f - p + 1e-8f));
    float pos = 0.25f * (1.0f - p) * (1.0f - p) * (-__logf(p + 1e-8f));
    return pos - neg;
}

// DPP-based f32 min step (VALU pipe, ~10-20 cy vs ~120 cy for ds_permute
// shuffles). 'old' = +INF bits so lanes with no valid DPP source contribute
// the min-identity. CTRL is a compile-time immediate (template).
template<int CTRL>
__device__ __forceinline__ float fmin_dpp(float v) {
    int t = __builtin_amdgcn_update_dpp(0x7F800000, __float_as_int(v),
                                        CTRL, 0xF, 0xF, false);
    return fminf(v, __int_as_float(t));
}

// One block per cost row (b,r): computes the row's costs, STORES them to
// global (L3-hot for search), and reduces min + first-index argmin exactly.
// 3200 blocks => full memory-latency hiding.
__global__ __launch_bounds__(256)
void rowmin_kernel(const float* __restrict__ rec, const float* __restrict__ loc,
                   const int* __restrict__ targets, float* __restrict__ cost_g,
                   float* __restrict__ rowmin_g, int* __restrict__ rowarg_g) {
    const int pid   = blockIdx.x;          // b*NT + r
    const int b     = pid / NT, r = pid % NT;
    const int tid   = threadIdx.x;
    const int qbase = tid << 2;
    const int tc    = targets[pid];

    float4 r4 = *(const float4*)(rec + ((size_t)b * CREC + tc) * QN + qbase);
    float4 l4 = *(const float4*)(loc + ((size_t)b * CLOC + r)  * QN + qbase);
    float4 c;
    c.x = 2.0f * focal_cost_f(r4.x) + focal_cost_f(l4.x);
    c.y = 2.0f * focal_cost_f(r4.y) + focal_cost_f(l4.y);
    c.z = 2.0f * focal_cost_f(r4.z) + focal_cost_f(l4.z);
    c.w = 2.0f * focal_cost_f(r4.w) + focal_cost_f(l4.w);
    *(float4*)(cost_g + ((size_t)pid << 10) + qbase) = c;

    float bv = c.x; int bq = qbase;
    if (c.y < bv) { bv = c.y; bq = qbase + 1; }     // strict < => first index
    if (c.z < bv) { bv = c.z; bq = qbase + 2; }
    if (c.w < bv) { bv = c.w; bq = qbase + 3; }
    #pragma unroll
    for (int off = 32; off; off >>= 1) {
        float ov = __shfl_xor(bv, off);
        int   oq = __shfl_xor(bq, off);
        if (ov < bv || (ov == bv && oq < bq)) { bv = ov; bq = oq; }
    }
    __shared__ float bmv[4];
    __shared__ int   bmq[4];
    if ((tid & 63) == 0) { bmv[tid >> 6] = bv; bmq[tid >> 6] = bq; }
    __syncthreads();
    if (tid == 0) {
        float fv = bmv[0]; int fq = bmq[0];
        #pragma unroll
        for (int w = 1; w < 4; ++w) {
            float ov = bmv[w]; int oq = bmq[w];
            if (ov < fv || (ov == fv && oq < fq)) { fv = ov; fq = oq; }
        }
        rowmin_g[pid] = fv; rowarg_g[pid] = fq;
    }
}

// ONE WAVE (64 threads) per batch: greedy tight assignment from row minima,
// then JV shortest-augmenting-path for argmin-collided rows. Thread t owns
// columns c == t (mod 64), 16 slots each. Cost slab prefetched into LDS
// (deep-pipelined, R8-verified). NEW vs R8: the per-iteration cross-lane
// reduction no longer uses ds_permute shuffles (~120 cy latency EACH; the
// 6-step dependent butterfly + resolve was ~960 cy, ~45% of the iteration
// chain — why R5/R7/R8's row-read changes were all null). Replaced with:
//   f32 screen: 6 DPP min steps on the VALU pipe (quad_perm xor1/xor2,
//     row_half_mirror, row_mirror, row_bcast15, row_bcast31 => lane 63
//     holds the wave min; +INF 'old' makes invalid lanes min-identity),
//     then one readlane(63) broadcast.
//   exact resolve: readlane x3 per screen candidate (lane idx is uniform).
// Monotone f32 screen + exact f64 resolve semantics are UNCHANGED => same
// candidates, same lexicographic winner => identical assignment as the
// verified R0/R5/R7/R8 kernels (= scipy's unique optimum).
__global__ __launch_bounds__(64)
void search_kernel(const float* __restrict__ cost_g,
                   const float* __restrict__ rowmin_g, const int* __restrict__ rowarg_g,
                   int* __restrict__ pairq_g) {
    const int b    = blockIdx.x;
    const int lane = threadIdx.x;        // 0..63

    extern __shared__ float cost_s[];    // f32[NT*QN] = 100 KB dynamic
    __shared__ int    way_s[QN + 1];
    __shared__ int    p_s[QN + 1];
    __shared__ double u_s[NT + 1];
    __shared__ float  rowmin_s[NT];
    __shared__ int    rowarg_s[NT];
    __shared__ int    unassigned_s[NT];
    __shared__ int    nun_s;

    for (int j = lane; j <= QN; j += 64) p_s[j] = 0;
    if (lane < NT) {
        rowmin_s[lane] = rowmin_g[b * NT + lane];
        rowarg_s[lane] = rowarg_g[b * NT + lane];
    }
    __syncthreads();

    // greedy tight assignment (serial, trivial)
    if (lane == 0) {
        int nun = 0;
        for (int r = 0; r < NT; ++r) {
            u_s[r + 1] = (double)rowmin_s[r];
            int j = rowarg_s[r] + 1;
            if (p_s[j] == 0) p_s[j] = r + 1;
            else             unassigned_s[nun++] = r + 1;
        }
        nun_s = nun;
    }
    __syncthreads();
    const int nun = nun_s;

    if (nun > 0) {
        // deep-pipelined prefetch: 6400 float4 total / 64 lanes = 100 per
        // lane, in 5 chunks of 20 (20 loads in flight per chunk => one
        // round-trip each; all indices static => registers, no scratch)
        const float4* src = (const float4*)(cost_g + ((size_t)b * NT << 10));
        float4*       dst = (float4*)cost_s;
        #pragma unroll
        for (int ch = 0; ch < 5; ++ch) {
            float4 tmp[20];
            #pragma unroll
            for (int it = 0; it < 20; ++it)
                tmp[it] = src[(ch * 20 + it) * 64 + lane];
            #pragma unroll
            for (int it = 0; it < 20; ++it)
                dst[(ch * 20 + it) * 64 + lane] = tmp[it];
        }
        __syncthreads();

        double v[16];
        #pragma unroll
        for (int m = 0; m < 16; ++m) v[m] = 0.0;

        for (int s = 0; s < nun; ++s) {
            const int i = unassigned_s[s];
            double minv[16], snap[16];
            #pragma unroll
            for (int m = 0; m < 16; ++m) { minv[m] = INFD; snap[m] = 0.0; }
            double dsum = 0.0;
            unsigned usedmask = 0;
            int j0 = 0;

            for (;;) {
                int i0;
                if (j0 == 0) {
                    i0 = i;
                } else {
                    int q0 = j0 - 1;
                    if ((q0 & 63) == lane) {         // owner lane of column q0
                        int mm = q0 >> 6;
                        usedmask |= 1u << mm;
                        #pragma unroll                // static indices only
                        for (int m = 0; m < 16; ++m)
                            if (m == mm) { minv[m] = INFD; snap[m] = dsum; }
                    }
                    i0 = p_s[j0];                    // p stable within a search
                }
                const double ui0 = u_s[i0];          // pre-search value (read-only in-loop)
                const float* rowp = cost_s + ((i0 - 1) << 10);
                float cf[16];
                #pragma unroll                        // conflict-free: lanes hit consecutive dwords
                for (int m = 0; m < 16; ++m) cf[m] = rowp[(m << 6) + lane];

                // relax own free columns; lane-local lexicographic argmin
                // (ascending m == ascending j within a lane)
                double bestv = INFD; int bestj = QN + 2;
                #pragma unroll
                for (int m = 0; m < 16; ++m) {
                    if (!(usedmask & (1u << m))) {
                        const int j = (m << 6) + lane + 1;
                        double cur = (double)cf[m] - ui0 - v[m];
                        if (cur < minv[m]) { minv[m] = cur; way_s[j] = j0; }
                        double mv = minv[m];
                        if (mv < bestv || (mv == bestv && j < bestj)) { bestv = mv; bestj = j; }
                    }
                }

                // f32 monotone screen via DPP (VALU pipe; lane 63 ends with
                // the wave-wide min), broadcast via readlane.
                float own32 = (float)bestv;
                float rmin = own32;
                rmin = fmin_dpp<0xB1>(rmin);    // quad_perm [1,0,3,2] : xor1
                rmin = fmin_dpp<0x4E>(rmin);    // quad_perm [2,3,0,1] : xor2
                rmin = fmin_dpp<0x141>(rmin);   // row_half_mirror     : min-8
                rmin = fmin_dpp<0x140>(rmin);   // row_mirror          : min-16
                rmin = fmin_dpp<0x142>(rmin);   // row_bcast15         : rows fwd
                rmin = fmin_dpp<0x143>(rmin);   // row_bcast31 => lane63 global
                float w32 = __int_as_float(
                    __builtin_amdgcn_readlane(__float_as_int(rmin), 63));

                // exact f64 resolve among screen candidates via readlane
                // (candidate lane index is wave-uniform from the ballot)
                unsigned long long cand = __ballot(own32 == w32);
                double wv = INFD; int wj = QN + 2;
                while (cand) {                       // ~1 iteration typical
                    int l = __ffsll(cand) - 1; cand &= cand - 1;
                    long long bb = __double_as_longlong(bestv);
                    int lo = __builtin_amdgcn_readlane((int)(bb & 0xFFFFFFFFLL), l);
                    int hi = __builtin_amdgcn_readlane((int)(bb >> 32), l);
                    double vv = __longlong_as_double(
                        ((long long)hi << 32) | (unsigned int)lo);
                    int jj = __builtin_amdgcn_readlane(bestj, l);
                    if (vv < wv || (vv == wv && jj < wj)) { wv = vv; wj = jj; }
                }
                const double delta = wv; const int j1 = wj;
                dsum += delta;

                #pragma unroll
                for (int m = 0; m < 16; ++m) {
                    if (usedmask & (1u << m)) v[m]    -= delta;
                    else                      minv[m] -= delta;
                }
                j0 = j1;
                if (p_s[j0] == 0) break;
            }

            // end-of-search u updates: distinct used columns => distinct
            // assigned rows => distinct LDS addresses, no race
            if (lane == 0) u_s[i] += dsum;
            unsigned mm = usedmask;
            while (mm) {
                int m = __ffs(mm) - 1; mm &= mm - 1;
                u_s[p_s[(m << 6) + lane + 1]] += dsum - snap[m];
            }
            __syncthreads();   // way_s/u_s visible to lane 0 (1-wave: cheap)
            // augment along the alternating path (short, sequential)
            if (lane == 0) {
                int jj = j0;
                while (jj != 0) {
                    int jn = way_s[jj];
                    p_s[jj] = (jn == 0) ? i : p_s[jn];
                    jj = jn;
                }
            }
            __syncthreads();   // p_s visible to all lanes for next search
        }
    }

    // emit matched pairs: column j assigned to target row p_s[j]-1
    for (int j = lane + 1; j <= QN; j += 64)
        if (p_s[j] > 0) pairq_g[b * NT + (p_s[j] - 1)] = j - 1;
}

// One wave per matched pair: CE over 107 (rec) and 25 (loc) classes at the
// matched query column. 3200 blocks => full latency hiding for the gathers.
// NO fences/atomics here — R3 showed per-block __threadfence() costs ~130 us
// (3200 device-scope flushes on non-coherent XCD L2s). The cross-kernel
// handoff to finalize_kernel does the cache maintenance ONCE at the boundary.
__global__ __launch_bounds__(64)
void loss_kernel(const float* __restrict__ rec, const float* __restrict__ loc,
                 const int* __restrict__ targets, const int* __restrict__ pairq_g,
                 float* __restrict__ partial) {
    const int pid  = blockIdx.x;          // b*NT + t
    const int b    = pid / NT, t = pid % NT;
    const int lane = threadIdx.x;
    const int q    = pairq_g[pid];

    // rec CE over 107 classes at query q
    const float* rb = rec + (size_t)b * CREC * QN + q;
    float x0 = (lane < CREC)      ? rb[(size_t)lane * QN]        : -1e30f;
    float x1 = (lane + 64 < CREC) ? rb[(size_t)(lane + 64) * QN] : -1e30f;
    float mx = fmaxf(x0, x1);
    #pragma unroll
    for (int off = 32; off; off >>= 1) mx = fmaxf(mx, __shfl_xor(mx, off));
    float e = 0.0f;
    if (lane < CREC)      e += expf(x0 - mx);
    if (lane + 64 < CREC) e += expf(x1 - mx);
    #pragma unroll
    for (int off = 32; off; off >>= 1) e += __shfl_xor(e, off);
    float lse = mx + logf(e);

    // loc CE over 25 classes at query q, label = t
    const float* lb = loc + (size_t)b * CLOC * QN + q;
    float y = (lane < CLOC) ? lb[(size_t)lane * QN] : -1e30f;
    float my = y;
    #pragma unroll
    for (int off = 32; off; off >>= 1) my = fmaxf(my, __shfl_xor(my, off));
    float ey = (lane < CLOC) ? expf(y - my) : 0.0f;
    #pragma unroll
    for (int off = 32; off; off >>= 1) ey += __shfl_xor(ey, off);
    float lsey = my + logf(ey);

    if (lane == 0) {
        int lab = targets[pid];
        partial[pid]           = lse  - rb[(size_t)lab * QN];
        partial[BS * NT + pid] = lsey - lb[(size_t)t * QN];
    }
}

__global__ __launch_bounds__(256)
void finalize_kernel(const float* __restrict__ partial, float* __restrict__ out) {
    const int tid = threadIdx.x;
    float s0 = 0.0f, s1 = 0.0f;
    for (int i = tid; i < BS * NT; i += 256) {
        s0 += partial[i];
        s1 += partial[BS * NT + i];
    }
    __shared__ float a0[4], a1[4];
    #pragma unroll
    for (int off = 32; off; off >>= 1) { s0 += __shfl_xor(s0, off); s1 += __shfl_xor(s1, off); }
    if ((tid & 63) == 0) { a0[tid >> 6] = s0; a1[tid >> 6] = s1; }
    __syncthreads();
    if (tid == 0) {
        out[0] = (a0[0] + a0[1] + a0[2] + a0[3]) * (1.0f / (BS * NT));
        out[1] = (a1[0] + a1[1] + a1[2] + a1[3]) * (1.0f / (BS * NT));
    }
}

extern "C" void kernel_launch(void* const* d_in, const int* in_sizes, int n_in,
                              void* d_out, int out_size, void* d_ws, size_t ws_size,
                              hipStream_t stream) {
    (void)in_sizes; (void)n_in; (void)out_size; (void)ws_size;
    const float* rec     = (const float*)d_in[0];
    const float* loc     = (const float*)d_in[1];
    const int*   targets = (const int*)d_in[2];
    float* out = (float*)d_out;

    // ws layout: cost f32[BS*NT*QN]=13.1MB | rowmin f32[3200] | rowarg i32[3200]
    //            | pairq i32[3200] | partial f32[6400]
    float* cost_g   = (float*)d_ws;
    float* rowmin_g = cost_g + (size_t)BS * NT * QN;
    int*   rowarg_g = (int*)(rowmin_g + BS * NT);
    int*   pairq_g  = rowarg_g + BS * NT;
    float* partial  = (float*)(pairq_g + BS * NT);

    // >64KB dynamic LDS opt-in for search (host-side attribute; not a
    // stream op — safe under graph capture).
    static bool attr_set = false;
    if (!attr_set) {
        (void)hipFuncSetAttribute((const void*)search_kernel,
                                  hipFuncAttributeMaxDynamicSharedMemorySize,
                                  (int)(NT * QN * sizeof(float)));
        attr_set = true;
    }

    hipLaunchKernelGGL(rowmin_kernel, dim3(BS * NT), dim3(256), 0, stream,
                       rec, loc, targets, cost_g, rowmin_g, rowarg_g);
    hipLaunchKernelGGL(search_kernel, dim3(BS), dim3(64),
                       NT * QN * sizeof(float), stream,
                       cost_g, rowmin_g, rowarg_g, pairq_g);
    hipLaunchKernelGGL(loss_kernel, dim3(BS * NT), dim3(64), 0, stream,
                       rec, loc, targets, pairq_g, partial);
    hipLaunchKernelGGL(finalize_kernel, dim3(1), dim3(256), 0, stream,
                       partial, out);
}